// Round 8
// baseline (86.522 us; speedup 1.0000x reference)
//
#include <hip/hip_runtime.h>
#include <stdint.h>

#define BN       16384
#define NTILES   256     // BN/64
#define NB       64      // norm buckets
#define KOUT     16
#define MARGIN   0.01f   // certified slack >> max fp32 eval error (~4e-5)

#define MAGIC1   0x5AFEC0DEu
#define MAGIC2   0xC001D00Du

typedef float v2f __attribute__((ext_vector_type(2)));
union F4 { float4 f4; v2f p[2]; float f[4]; };

// ---- workspace layout (bytes) ----
#define WS_TAB    0                         // float4[BN]    262144
#define WS_IDX    (WS_TAB + BN * 16)        // u16[BN]        32768 (slot kept 64KB)
#define WS_BND    (WS_IDX + BN * 4)         // float2[NTILES]  2048
#define WS_FLG    0x60000                   // u64[64]          512  (isolated page)
#define WS_HIST   0x70000                   // u32[64][NB]    16384
#define WS_HMAX   (WS_HIST + 64 * NB * 4)   // u32[64][NB]    16384

// sortable key of float bits (ascending uint == ascending float)
__device__ __forceinline__ unsigned key_u(unsigned u) {
    return u ^ ((unsigned)((int)u >> 31) | 0x80000000u);
}
__device__ __forceinline__ unsigned wshr1(unsigned v, unsigned oldv) {
    return (unsigned)__builtin_amdgcn_update_dpp((int)oldv, (int)v, 0x138 /*WAVE_SHR:1*/,
                                                 0xF, 0xF, false);
}
#define RL16(T) __uint_as_float((unsigned)__builtin_amdgcn_readlane(__float_as_int(T), 16))

// exact np-order squared norm: (x^2 + y^2) + z^2
__device__ __forceinline__ float sq_of(float gx, float gy, float gz) {
    return __fadd_rn(__fadd_rn(__fmul_rn(gx, gx), __fmul_rn(gy, gy)), __fmul_rn(gz, gz));
}
__device__ __forceinline__ int bucket_of(float sq) {
    const float rho = __fsqrt_rn(sq);
    int b = (int)(64.0f * (1.0f - rho * 0.2f));  // edges rho_b = 5*(1-b/64)
    return (b < 0) ? 0 : ((b > 63) ? 63 : b);
}

// Lexicographic (pair asc, idx asc) sorted insert -> scan-order independent.
#define DRAIN(m, p, jvec, T, J)                                                     \
    while (m) {                                                                     \
        const int b_ = (int)__builtin_ctzll(m);                                     \
        m &= m - 1;                                                                 \
        const float pc_ = __uint_as_float(                                          \
            (unsigned)__builtin_amdgcn_readlane(__float_as_int(p), b_));            \
        const unsigned jc_ = (unsigned)__builtin_amdgcn_readlane((int)(jvec), b_);  \
        const float Tup_ =                                                          \
            __uint_as_float(wshr1(__float_as_uint(T), 0xFF800000u /*-inf*/));       \
        const unsigned Jup_ = wshr1((J), 0u);                                       \
        const bool lt_ = (pc_ < Tup_) || ((pc_ == Tup_) && (jc_ < Jup_));           \
        const float Tn_ = lt_ ? Tup_ : pc_;                                         \
        const unsigned Jn_ = lt_ ? Jup_ : jc_;                                      \
        const bool sel_ = (pc_ < (T)) || ((pc_ == (T)) && (jc_ < (J)));             \
        (T) = sel_ ? Tn_ : (T);                                                     \
        (J) = sel_ ? Jn_ : (J);                                                     \
    }

// d2 = ((2*dot + nsq_q) + nsq_j) packed for 2 queries, bitwise == reference chain.
#define EVALC(c, d2)                                                                \
    asm("v_pk_mul_f32 %0, %1, %2 op_sel:[0,0] op_sel_hi:[0,1]"                      \
        : "=v"(d2) : "v"((c).p[0]), "v"(c0A));                                      \
    asm("v_pk_fma_f32 %0, %1, %2, %0 op_sel:[1,0,0] op_sel_hi:[1,1,1]"              \
        : "+v"(d2) : "v"((c).p[0]), "v"(c1A));                                      \
    asm("v_pk_fma_f32 %0, %1, %2, %0 op_sel:[0,0,0] op_sel_hi:[0,1,1]"              \
        : "+v"(d2) : "v"((c).p[1]), "v"(c2A));                                      \
    asm("v_pk_add_f32 %0, %0, %1" : "+v"(d2) : "v"(nsq01));                         \
    asm("v_pk_add_f32 %0, %0, %1 op_sel:[0,1] op_sel_hi:[1,1]"                      \
        : "+v"(d2) : "v"((c).p[1]));

// certificate test for the 64 tiles held in register pair bd (lane l = tile l of chunk)
#define CERTM(bd)                                                                    \
    __ballot((__builtin_fmaf(twor0, (bd)[1], __fadd_rn(sq0, (bd)[0])) < thr0) &&     \
             (__builtin_fmaf(twor1, (bd)[1], __fadd_rn(sq1, (bd)[0])) < thr1))

#define COMPUTE_TSTAR()                                                              \
    do {                                                                             \
        uint64_t mm;                                                                 \
        if ((mm = CERTM(bdA)))        ts = (int)__builtin_ctzll(mm);                 \
        else if ((mm = CERTM(bdB)))   ts = 64  + (int)__builtin_ctzll(mm);           \
        else if ((mm = CERTM(bdC)))   ts = 128 + (int)__builtin_ctzll(mm);           \
        else if ((mm = CERTM(bdD)))   ts = 192 + (int)__builtin_ctzll(mm);           \
        else                          ts = NTILES;                                   \
    } while (0)

// process one pre-loaded tile; index load DEFERRED into the (wave-uniform) hit branch
#define PROC1(c, t)                                                                  \
    {                                                                                \
        v2f d2; EVALC(c, d2)                                                         \
        uint64_t m0 = __ballot(d2[0] <= fF0);                                        \
        uint64_t m1 = __ballot(d2[1] <= fF1);                                        \
        if (m0 | m1) {                                                               \
            const unsigned jvec = (unsigned)idx16[(t) * 64 + lane];                  \
            const float p0v = d2[0], p1v = d2[1];                                    \
            DRAIN(m0, p0v, jvec, T0, J0)                                             \
            DRAIN(m1, p1v, jvec, T1, J1)                                             \
            fF0 = RL16(T0); thr0 = __fsub_rn(-fF0, MARGIN);                          \
            fF1 = RL16(T1); thr1 = __fsub_rn(-fF1, MARGIN);                          \
            COMPUTE_TSTAR();                                                         \
        }                                                                            \
    }

// Joint wave-parallel exact sort of 64 (p0,j) and 64 (p1,j) pairs by (p asc, j asc):
// ONE shared 63-iter rank loop for both queries (u64 keys, unique by j). — R7 verbatim
__device__ __forceinline__ void presort2(float p0, float p1, unsigned j, int lane,
                                         uint4* sw,
                                         float& T0c, unsigned& J0c,
                                         float& T1c, unsigned& J1c) {
    const unsigned kp0 = key_u(__float_as_uint(p0));
    const unsigned kp1 = key_u(__float_as_uint(p1));
    const unsigned long long k0 = ((unsigned long long)kp0 << 32) | (unsigned long long)j;
    const unsigned long long k1 = ((unsigned long long)kp1 << 32) | (unsigned long long)j;
    sw[lane] = make_uint4(j, kp0, j, kp1);
    unsigned r0 = 0u, r1 = 0u;
    unsigned off = (unsigned)lane;
#pragma unroll 7
    for (int s = 1; s < 64; ++s) {
        off = (off + 1u) & 63u;
        const uint4 o = sw[off];
        const unsigned long long o0 = ((unsigned long long)o.y << 32) | (unsigned long long)o.x;
        const unsigned long long o1 = ((unsigned long long)o.w << 32) | (unsigned long long)o.z;
        r0 += (o0 < k0) ? 1u : 0u;
        r1 += (o1 < k1) ? 1u : 0u;
    }
    unsigned long long* s0 = (unsigned long long*)sw;   // u64[0..63]   : q0 sorted
    unsigned long long* s1 = s0 + 64;                   // u64[64..127] : q1 sorted
    s0[r0] = k0;
    s1[r1] = k1;
    const unsigned long long v0 = s0[lane];
    const unsigned long long v1 = s1[lane];
    const unsigned kq0 = (unsigned)(v0 >> 32), kq1 = (unsigned)(v1 >> 32);
    T0c = __uint_as_float((kq0 & 0x80000000u) ? (kq0 ^ 0x80000000u) : ~kq0);
    J0c = (unsigned)(v0 & 0xFFFFFFFFull);
    T1c = __uint_as_float((kq1 & 0x80000000u) ? (kq1 ^ 0x80000000u) : ~kq1);
    J1c = (unsigned)(v1 & 0xFFFFFFFFull);
}

// ---- fused prep, 64 blocks (all trivially co-resident -> spin is deadlock-free).
// Phase A: per-block hist/max -> IF via agent-scope stores; fused double-magic u64
// flag (poison cannot match). Single-lane relaxed polling + one fence. Phase B:
// plain WIDE loads (reader L1/L2 hold no line for hist: kernel-start acquire
// invalidated, nothing reads it pre-barrier) -> bases + scatter + bnd,
// math identical to the R7 two-kernel version. ----
__global__ __launch_bounds__(256) void k_prep_f2(const float* __restrict__ x,
                                                 unsigned* __restrict__ hist,
                                                 unsigned* __restrict__ hmax,
                                                 unsigned long long* __restrict__ flg,
                                                 float4* __restrict__ tab,
                                                 unsigned short* __restrict__ idx16,
                                                 float2* __restrict__ bnd) {
    __shared__ unsigned h[NB], m[NB];
    __shared__ unsigned colbase[NB], cur[NB], basev[NB + 1], mxv[NB], sfxs[NB];
    const int tid = threadIdx.x;
    const int blk = blockIdx.x;
    if (tid < NB) { h[tid] = 0u; m[tid] = 0u; }
    __syncthreads();

    // phase A: this block's 256 points
    const int i = blk * 256 + tid;
    const float gx = x[3 * i], gy = x[3 * i + 1], gz = x[3 * i + 2];
    const float sq = sq_of(gx, gy, gz);
    const int b = bucket_of(sq);
    atomicAdd(&h[b], 1u);
    atomicMax(&m[b], __float_as_uint(sq));  // sq>0: float bits monotone
    __syncthreads();
    if (tid < NB) {   // agent-scope stores: visible at coherence point
        __hip_atomic_store(&hist[blk * NB + tid], h[tid],
                           __ATOMIC_RELAXED, __HIP_MEMORY_SCOPE_AGENT);
        __hip_atomic_store(&hmax[blk * NB + tid], m[tid],
                           __ATOMIC_RELAXED, __HIP_MEMORY_SCOPE_AGENT);
    }
    __syncthreads();  // s_waitcnt vmcnt(0): all 128 stores complete before flag
    if (tid == 0) {
        const unsigned long long fv =
            ((unsigned long long)(MAGIC2 ^ (unsigned)blk) << 32) |
            (unsigned long long)(MAGIC1 + (unsigned)blk);
        __hip_atomic_store(&flg[blk], fv, __ATOMIC_RELEASE, __HIP_MEMORY_SCOPE_AGENT);
        // single-lane relaxed polling with backoff (no acquire storm)
        for (int t = 0; t < NB; ++t) {
            const unsigned long long want =
                ((unsigned long long)(MAGIC2 ^ (unsigned)t) << 32) |
                (unsigned long long)(MAGIC1 + (unsigned)t);
            while (__hip_atomic_load(&flg[t], __ATOMIC_RELAXED,
                                     __HIP_MEMORY_SCOPE_AGENT) != want) {
                __builtin_amdgcn_s_sleep(16);
            }
        }
        __threadfence();
    }
    __syncthreads();

    // phase B: plain wide reads (L2-cached), reduction -> bases, scatter
    if (tid < NB) {
        unsigned tot = 0u, part = 0u, mx = 0u;
#pragma unroll 8
        for (int g = 0; g < 64; ++g) {
            const unsigned hh = hist[g * NB + tid];
            tot += hh;
            part += (g < blk) ? hh : 0u;
            const unsigned w = hmax[g * NB + tid];
            mx = (w > mx) ? w : mx;
        }
        unsigned v = tot;
#pragma unroll
        for (int s = 1; s < 64; s <<= 1) {
            const unsigned n = (unsigned)__shfl_up((int)v, (unsigned)s, 64);
            v += (tid >= s) ? n : 0u;
        }
        basev[tid] = v - tot;  // exclusive prefix
        if (tid == NB - 1) basev[NB] = v;
        colbase[tid] = (v - tot) + part;
        cur[tid] = 0u;
        mxv[tid] = mx;
    }
    __syncthreads();
    const unsigned r = atomicAdd(&cur[b], 1u);
    const unsigned pos = colbase[b] + r;
    tab[pos] = make_float4(gx, gy, gz, -sq);
    idx16[pos] = (unsigned short)i;

    if (blk == 0) {  // block-uniform branch: syncthreads inside is legal
        if (tid == 0) {
            unsigned M = 0u;
            for (int b2 = NB - 1; b2 >= 0; --b2) {
                const unsigned w = mxv[b2];
                M = (w > M) ? w : M;
                sfxs[b2] = M;
            }
        }
        __syncthreads();
        const unsigned posb = (unsigned)tid * 64u;
        int bb = 0;
        for (int t2 = 0; t2 < NB; ++t2)
            if (basev[t2] <= posb && posb < basev[t2 + 1]) bb = t2;
        const float B = __uint_as_float(sfxs[bb]);
        const float sqB_up = __uint_as_float(__float_as_uint(__fsqrt_rn(B)) + 2u);
        bnd[tid] = make_float2(B, sqB_up);
    }
}

// ---- main kernel: R7 verbatim (joint-rank seed sort, 4-wide prefetch) ----
__global__ __launch_bounds__(256) void knn_far_kernel(
    const float4* __restrict__ tab, const unsigned short* __restrict__ idx16,
    const float2* __restrict__ bnd, float* __restrict__ out_d, float* __restrict__ out_i) {
    __shared__ uint4 swall[4][64];   // 1 KB per wave (keys, then 2x u64 sorted rows)
    const int tid  = threadIdx.x;
    const int lane = tid & 63;
    const int wid  = tid >> 6;
    uint4* sw = swall[wid];
    const int p0 = (blockIdx.x * 4 + wid) * 2;
    const int p1 = p0 + 1;

    F4 qa; qa.f4 = tab[p0];
    F4 qb; qb.f4 = tab[p1];
    const unsigned q0 = (unsigned)idx16[p0];
    const unsigned q1 = (unsigned)idx16[p1];
    const float sq0 = -qa.f[3], sq1 = -qb.f[3];        // tab.w = -sq (exact)
    const v2f nsq01 = {qa.f[3], qb.f[3]};              // {-sq0, -sq1}
    const v2f c0A = {2.0f * qa.f[0], 2.0f * qb.f[0]};
    const v2f c1A = {2.0f * qa.f[1], 2.0f * qb.f[1]};
    const v2f c2A = {2.0f * qa.f[2], 2.0f * qb.f[2]};
    const float twor0 = 2.0f * __uint_as_float(__float_as_uint(__fsqrt_rn(sq0)) + 2u);
    const float twor1 = 2.0f * __uint_as_float(__float_as_uint(__fsqrt_rn(sq1)) + 2u);

    const v2f* bndv = (const v2f*)bnd;
    const v2f bdA = bndv[lane];
    const v2f bdB = bndv[64 + lane];
    const v2f bdC = bndv[128 + lane];
    const v2f bdD = bndv[192 + lane];

    float T0, T1; unsigned J0, J1;
    float fF0, fF1, thr0, thr1;
    int ts = NTILES;

    {   // seed region (tiles 0..3, top-256 norms)
        F4 s0_, s1_, s2_, s3_;
        s0_.f4 = tab[0 * 64 + lane];
        s1_.f4 = tab[1 * 64 + lane];
        s2_.f4 = tab[2 * 64 + lane];
        s3_.f4 = tab[3 * 64 + lane];
        const unsigned jv0 = (unsigned)idx16[lane];
        {
            v2f d2; EVALC(s0_, d2)
            presort2(d2[0], d2[1], jv0, lane, sw, T0, J0, T1, J1);
            fF0 = RL16(T0); thr0 = __fsub_rn(-fF0, MARGIN);
            fF1 = RL16(T1); thr1 = __fsub_rn(-fF1, MARGIN);
        }
        PROC1(s1_, 1)
        PROC1(s2_, 2)
        PROC1(s3_, 3)
    }

    COMPUTE_TSTAR();  // first tile certified for BOTH queries (exact, monotone)

    for (int t = 4; t < ts; t += 4) {
        F4 cA_, cB_, cC_, cD_;
        cA_.f4 = tab[(t + 0) * 64 + lane];
        cB_.f4 = tab[(t + 1) * 64 + lane];
        cC_.f4 = tab[(t + 2) * 64 + lane];
        cD_.f4 = tab[(t + 3) * 64 + lane];
        PROC1(cA_, t + 0)
        PROC1(cB_, t + 1)
        PROC1(cC_, t + 2)
        PROC1(cD_, t + 3)
    }

    if (lane >= 1 && lane <= KOUT) {  // ranks 1..16 (rank 0 dropped by reference)
        const int r = lane - 1;
        out_d[q0 * KOUT + r] = T0;
        out_i[q0 * KOUT + r] = (float)J0;
        out_d[q1 * KOUT + r] = T1;
        out_i[q1 * KOUT + r] = (float)J1;
    }
}

extern "C" void kernel_launch(void* const* d_in, const int* in_sizes, int n_in,
                              void* d_out, int out_size, void* d_ws, size_t ws_size,
                              hipStream_t stream) {
    const float* x = (const float*)d_in[0];
    char* ws = (char*)d_ws;
    float4*             tab   = (float4*)(ws + WS_TAB);
    unsigned short*     idx16 = (unsigned short*)(ws + WS_IDX);
    float2*             bnd   = (float2*)(ws + WS_BND);
    unsigned long long* flg   = (unsigned long long*)(ws + WS_FLG);
    unsigned*           hist  = (unsigned*)(ws + WS_HIST);
    unsigned*           hmax  = (unsigned*)(ws + WS_HMAX);
    float* out_d = (float*)d_out;
    float* out_i = out_d + (size_t)BN * KOUT;

    hipLaunchKernelGGL(k_prep_f2, dim3(64), dim3(256), 0, stream,
                       x, hist, hmax, flg, tab, idx16, bnd);
    hipLaunchKernelGGL(knn_far_kernel, dim3(BN / 8), dim3(256), 0, stream,
                       tab, idx16, bnd, out_d, out_i);
}

// Round 9
// 76.658 us; speedup vs baseline: 1.1287x; 1.1287x over previous
//
#include <hip/hip_runtime.h>
#include <stdint.h>

#define BN       16384
#define NTILES   256     // BN/64
#define NB       64      // norm buckets
#define KOUT     16
#define MARGIN   0.01f   // certified slack >> max fp32 eval error (~4e-5)

typedef float v2f __attribute__((ext_vector_type(2)));
union F4 { float4 f4; v2f p[2]; float f[4]; };

// ---- workspace layout (bytes) ----
#define WS_TAB    0                         // float4[BN]    262144
#define WS_IDX    (WS_TAB + BN * 16)        // u16[BN]        32768
#define WS_BND    (WS_IDX + BN * 4)         // float2[NTILES]  2048

// sortable key of float bits (ascending uint == ascending float)
__device__ __forceinline__ unsigned key_u(unsigned u) {
    return u ^ ((unsigned)((int)u >> 31) | 0x80000000u);
}
__device__ __forceinline__ unsigned wshr1(unsigned v, unsigned oldv) {
    return (unsigned)__builtin_amdgcn_update_dpp((int)oldv, (int)v, 0x138 /*WAVE_SHR:1*/,
                                                 0xF, 0xF, false);
}
#define RL16(T) __uint_as_float((unsigned)__builtin_amdgcn_readlane(__float_as_int(T), 16))

// exact np-order squared norm: (x^2 + y^2) + z^2
__device__ __forceinline__ float sq_of(float gx, float gy, float gz) {
    return __fadd_rn(__fadd_rn(__fmul_rn(gx, gx), __fmul_rn(gy, gy)), __fmul_rn(gz, gz));
}
__device__ __forceinline__ int bucket_of(float sq) {
    const float rho = __fsqrt_rn(sq);
    int b = (int)(64.0f * (1.0f - rho * 0.2f));  // edges rho_b = 5*(1-b/64)
    return (b < 0) ? 0 : ((b > 63) ? 63 : b);
}

// Lexicographic (pair asc, idx asc) sorted insert -> scan-order independent.
#define DRAIN(m, p, jvec, T, J)                                                     \
    while (m) {                                                                     \
        const int b_ = (int)__builtin_ctzll(m);                                     \
        m &= m - 1;                                                                 \
        const float pc_ = __uint_as_float(                                          \
            (unsigned)__builtin_amdgcn_readlane(__float_as_int(p), b_));            \
        const unsigned jc_ = (unsigned)__builtin_amdgcn_readlane((int)(jvec), b_);  \
        const float Tup_ =                                                          \
            __uint_as_float(wshr1(__float_as_uint(T), 0xFF800000u /*-inf*/));       \
        const unsigned Jup_ = wshr1((J), 0u);                                       \
        const bool lt_ = (pc_ < Tup_) || ((pc_ == Tup_) && (jc_ < Jup_));           \
        const float Tn_ = lt_ ? Tup_ : pc_;                                         \
        const unsigned Jn_ = lt_ ? Jup_ : jc_;                                      \
        const bool sel_ = (pc_ < (T)) || ((pc_ == (T)) && (jc_ < (J)));             \
        (T) = sel_ ? Tn_ : (T);                                                     \
        (J) = sel_ ? Jn_ : (J);                                                     \
    }

// d2 = ((2*dot + nsq_q) + nsq_j) packed for 2 queries, bitwise == reference chain.
#define EVALC(c, d2)                                                                \
    asm("v_pk_mul_f32 %0, %1, %2 op_sel:[0,0] op_sel_hi:[0,1]"                      \
        : "=v"(d2) : "v"((c).p[0]), "v"(c0A));                                      \
    asm("v_pk_fma_f32 %0, %1, %2, %0 op_sel:[1,0,0] op_sel_hi:[1,1,1]"              \
        : "+v"(d2) : "v"((c).p[0]), "v"(c1A));                                      \
    asm("v_pk_fma_f32 %0, %1, %2, %0 op_sel:[0,0,0] op_sel_hi:[0,1,1]"              \
        : "+v"(d2) : "v"((c).p[1]), "v"(c2A));                                      \
    asm("v_pk_add_f32 %0, %0, %1" : "+v"(d2) : "v"(nsq01));                         \
    asm("v_pk_add_f32 %0, %0, %1 op_sel:[0,1] op_sel_hi:[1,1]"                      \
        : "+v"(d2) : "v"((c).p[1]));

// certificate test for the 64 tiles held in register pair bd (lane l = tile l of chunk)
#define CERTM(bd)                                                                    \
    __ballot((__builtin_fmaf(twor0, (bd)[1], __fadd_rn(sq0, (bd)[0])) < thr0) &&     \
             (__builtin_fmaf(twor1, (bd)[1], __fadd_rn(sq1, (bd)[0])) < thr1))

#define COMPUTE_TSTAR()                                                              \
    do {                                                                             \
        uint64_t mm;                                                                 \
        if ((mm = CERTM(bdA)))        ts = (int)__builtin_ctzll(mm);                 \
        else if ((mm = CERTM(bdB)))   ts = 64  + (int)__builtin_ctzll(mm);           \
        else if ((mm = CERTM(bdC)))   ts = 128 + (int)__builtin_ctzll(mm);           \
        else if ((mm = CERTM(bdD)))   ts = 192 + (int)__builtin_ctzll(mm);           \
        else                          ts = NTILES;                                   \
    } while (0)

// process one pre-loaded tile; index load DEFERRED into the (wave-uniform) hit branch
#define PROC1(c, t)                                                                  \
    {                                                                                \
        v2f d2; EVALC(c, d2)                                                         \
        uint64_t m0 = __ballot(d2[0] <= fF0);                                        \
        uint64_t m1 = __ballot(d2[1] <= fF1);                                        \
        if (m0 | m1) {                                                               \
            const unsigned jvec = (unsigned)idx16[(t) * 64 + lane];                  \
            const float p0v = d2[0], p1v = d2[1];                                    \
            DRAIN(m0, p0v, jvec, T0, J0)                                             \
            DRAIN(m1, p1v, jvec, T1, J1)                                             \
            fF0 = RL16(T0); thr0 = __fsub_rn(-fF0, MARGIN);                          \
            fF1 = RL16(T1); thr1 = __fsub_rn(-fF1, MARGIN);                          \
            COMPUTE_TSTAR();                                                         \
        }                                                                            \
    }

// Joint wave-parallel exact sort of 64 (p0,j) and 64 (p1,j) pairs by (p asc, j asc)
// — R7 verbatim (shared 63-iter rank loop, u64 keys unique by j).
__device__ __forceinline__ void presort2(float p0, float p1, unsigned j, int lane,
                                         uint4* sw,
                                         float& T0c, unsigned& J0c,
                                         float& T1c, unsigned& J1c) {
    const unsigned kp0 = key_u(__float_as_uint(p0));
    const unsigned kp1 = key_u(__float_as_uint(p1));
    const unsigned long long k0 = ((unsigned long long)kp0 << 32) | (unsigned long long)j;
    const unsigned long long k1 = ((unsigned long long)kp1 << 32) | (unsigned long long)j;
    sw[lane] = make_uint4(j, kp0, j, kp1);
    unsigned r0 = 0u, r1 = 0u;
    unsigned off = (unsigned)lane;
#pragma unroll 7
    for (int s = 1; s < 64; ++s) {
        off = (off + 1u) & 63u;
        const uint4 o = sw[off];
        const unsigned long long o0 = ((unsigned long long)o.y << 32) | (unsigned long long)o.x;
        const unsigned long long o1 = ((unsigned long long)o.w << 32) | (unsigned long long)o.z;
        r0 += (o0 < k0) ? 1u : 0u;
        r1 += (o1 < k1) ? 1u : 0u;
    }
    unsigned long long* s0 = (unsigned long long*)sw;   // u64[0..63]   : q0 sorted
    unsigned long long* s1 = s0 + 64;                   // u64[64..127] : q1 sorted
    s0[r0] = k0;
    s1[r1] = k1;
    const unsigned long long v0 = s0[lane];
    const unsigned long long v1 = s1[lane];
    const unsigned kq0 = (unsigned)(v0 >> 32), kq1 = (unsigned)(v1 >> 32);
    T0c = __uint_as_float((kq0 & 0x80000000u) ? (kq0 ^ 0x80000000u) : ~kq0);
    J0c = (unsigned)(v0 & 0xFFFFFFFFull);
    T1c = __uint_as_float((kq1 & 0x80000000u) ? (kq1 ^ 0x80000000u) : ~kq1);
    J1c = (unsigned)(v1 & 0xFFFFFFFFull);
}

// ---- one-dispatch prep via REDUNDANT full histogram (no barrier, no atomics
// across blocks): each of 64 blocks (1024 thr) histograms ALL 16384 points into
// LDS hist[src_block][bucket], derives global bases + its own column offset, and
// scatters its own 256 points. Same FP chains as before -> bit-identical tab/bnd.
__global__ __launch_bounds__(1024) void k_prep_all(const float* __restrict__ x,
                                                   float4* __restrict__ tab,
                                                   unsigned short* __restrict__ idx16,
                                                   float2* __restrict__ bnd) {
    __shared__ unsigned hist[64][NB];   // 16 KB: [source block][bucket]
    __shared__ unsigned hm[NB];
    __shared__ unsigned basev[NB + 1], cursor[NB], sfxs[NB];
    const int tid = threadIdx.x;
    const int blk = blockIdx.x;
    {   // zero 4096 hist entries with 1024 threads
        unsigned* hf = &hist[0][0];
        hf[tid] = 0u; hf[tid + 1024] = 0u; hf[tid + 2048] = 0u; hf[tid + 3072] = 0u;
        if (tid < NB) hm[tid] = 0u;
    }
    __syncthreads();

    // full histogram: 16 consecutive points per thread (row = tid>>4, fixed),
    // float4-vectorized loads (3 float4 = 4 points).
    {
        const int row = tid >> 4;                  // (tid*16+j)>>8 for j<16
        const float4* xv = (const float4*)x + tid * 12;
#pragma unroll
        for (int g4 = 0; g4 < 4; ++g4) {
            const float4 f0 = xv[g4 * 3 + 0];
            const float4 f1 = xv[g4 * 3 + 1];
            const float4 f2 = xv[g4 * 3 + 2];
            float px[4], py[4], pz[4];
            px[0] = f0.x; py[0] = f0.y; pz[0] = f0.z;
            px[1] = f0.w; py[1] = f1.x; pz[1] = f1.y;
            px[2] = f1.z; py[2] = f1.w; pz[2] = f2.x;
            px[3] = f2.y; py[3] = f2.z; pz[3] = f2.w;
#pragma unroll
            for (int u = 0; u < 4; ++u) {
                const float sq = sq_of(px[u], py[u], pz[u]);
                const int b = bucket_of(sq);
                atomicAdd(&hist[row][b], 1u);
                atomicMax(&hm[b], __float_as_uint(sq));  // sq>0: bits monotone
            }
        }
    }
    __syncthreads();

    // wave 0: column totals + this block's partial, prefix scan -> bases/cursor
    if (tid < NB) {
        unsigned tot = 0u, part = 0u;
#pragma unroll 8
        for (int g = 0; g < 64; ++g) {
            const unsigned v = hist[g][tid];
            tot += v;
            part += (g < blk) ? v : 0u;
        }
        unsigned v = tot;
#pragma unroll
        for (int s = 1; s < 64; s <<= 1) {
            const unsigned n = (unsigned)__shfl_up((int)v, (unsigned)s, 64);
            v += (tid >= s) ? n : 0u;
        }
        basev[tid] = v - tot;                 // exclusive prefix of totals
        if (tid == NB - 1) basev[NB] = v;
        cursor[tid] = (v - tot) + part;       // this block's write base in bucket
    }
    if (tid == 64) {                          // wave 1, parallel with the scan
        unsigned M = 0u;
        for (int b2 = NB - 1; b2 >= 0; --b2) {
            const unsigned w = hm[b2];
            M = (w > M) ? w : M;
            sfxs[b2] = M;
        }
    }
    __syncthreads();

    // scatter own 256 points (threads 0..255; x re-read is L1/L2 hot, same FP chain)
    if (tid < 256) {
        const int i = blk * 256 + tid;
        const float gx = x[3 * i], gy = x[3 * i + 1], gz = x[3 * i + 2];
        const float sq = sq_of(gx, gy, gz);
        const int b = bucket_of(sq);
        const unsigned pos = atomicAdd(&cursor[b], 1u);
        tab[pos] = make_float4(gx, gy, gz, -sq);
        idx16[pos] = (unsigned short)i;
    }

    // per-tile bound (block 0, threads 0..255): same math/FP chain as before
    if (blk == 0 && tid < 256) {
        const unsigned posb = (unsigned)tid * 64u;
        int bb = 0;
        for (int t2 = 0; t2 < NB; ++t2)
            if (basev[t2] <= posb && posb < basev[t2 + 1]) bb = t2;
        const float B = __uint_as_float(sfxs[bb]);
        const float sqB_up = __uint_as_float(__float_as_uint(__fsqrt_rn(B)) + 2u);
        bnd[tid] = make_float2(B, sqB_up);
    }
}

// ---- main kernel: R7 verbatim (joint-rank seed sort, 4-wide prefetch) ----
__global__ __launch_bounds__(256) void knn_far_kernel(
    const float4* __restrict__ tab, const unsigned short* __restrict__ idx16,
    const float2* __restrict__ bnd, float* __restrict__ out_d, float* __restrict__ out_i) {
    __shared__ uint4 swall[4][64];
    const int tid  = threadIdx.x;
    const int lane = tid & 63;
    const int wid  = tid >> 6;
    uint4* sw = swall[wid];
    const int p0 = (blockIdx.x * 4 + wid) * 2;
    const int p1 = p0 + 1;

    F4 qa; qa.f4 = tab[p0];
    F4 qb; qb.f4 = tab[p1];
    const unsigned q0 = (unsigned)idx16[p0];
    const unsigned q1 = (unsigned)idx16[p1];
    const float sq0 = -qa.f[3], sq1 = -qb.f[3];        // tab.w = -sq (exact)
    const v2f nsq01 = {qa.f[3], qb.f[3]};              // {-sq0, -sq1}
    const v2f c0A = {2.0f * qa.f[0], 2.0f * qb.f[0]};
    const v2f c1A = {2.0f * qa.f[1], 2.0f * qb.f[1]};
    const v2f c2A = {2.0f * qa.f[2], 2.0f * qb.f[2]};
    const float twor0 = 2.0f * __uint_as_float(__float_as_uint(__fsqrt_rn(sq0)) + 2u);
    const float twor1 = 2.0f * __uint_as_float(__float_as_uint(__fsqrt_rn(sq1)) + 2u);

    const v2f* bndv = (const v2f*)bnd;
    const v2f bdA = bndv[lane];
    const v2f bdB = bndv[64 + lane];
    const v2f bdC = bndv[128 + lane];
    const v2f bdD = bndv[192 + lane];

    float T0, T1; unsigned J0, J1;
    float fF0, fF1, thr0, thr1;
    int ts = NTILES;

    {   // seed region (tiles 0..3, top-256 norms)
        F4 s0_, s1_, s2_, s3_;
        s0_.f4 = tab[0 * 64 + lane];
        s1_.f4 = tab[1 * 64 + lane];
        s2_.f4 = tab[2 * 64 + lane];
        s3_.f4 = tab[3 * 64 + lane];
        const unsigned jv0 = (unsigned)idx16[lane];
        {
            v2f d2; EVALC(s0_, d2)
            presort2(d2[0], d2[1], jv0, lane, sw, T0, J0, T1, J1);
            fF0 = RL16(T0); thr0 = __fsub_rn(-fF0, MARGIN);
            fF1 = RL16(T1); thr1 = __fsub_rn(-fF1, MARGIN);
        }
        PROC1(s1_, 1)
        PROC1(s2_, 2)
        PROC1(s3_, 3)
    }

    COMPUTE_TSTAR();  // first tile certified for BOTH queries (exact, monotone)

    for (int t = 4; t < ts; t += 4) {
        F4 cA_, cB_, cC_, cD_;
        cA_.f4 = tab[(t + 0) * 64 + lane];
        cB_.f4 = tab[(t + 1) * 64 + lane];
        cC_.f4 = tab[(t + 2) * 64 + lane];
        cD_.f4 = tab[(t + 3) * 64 + lane];
        PROC1(cA_, t + 0)
        PROC1(cB_, t + 1)
        PROC1(cC_, t + 2)
        PROC1(cD_, t + 3)
    }

    if (lane >= 1 && lane <= KOUT) {  // ranks 1..16 (rank 0 dropped by reference)
        const int r = lane - 1;
        out_d[q0 * KOUT + r] = T0;
        out_i[q0 * KOUT + r] = (float)J0;
        out_d[q1 * KOUT + r] = T1;
        out_i[q1 * KOUT + r] = (float)J1;
    }
}

extern "C" void kernel_launch(void* const* d_in, const int* in_sizes, int n_in,
                              void* d_out, int out_size, void* d_ws, size_t ws_size,
                              hipStream_t stream) {
    const float* x = (const float*)d_in[0];
    char* ws = (char*)d_ws;
    float4*         tab   = (float4*)(ws + WS_TAB);
    unsigned short* idx16 = (unsigned short*)(ws + WS_IDX);
    float2*         bnd   = (float2*)(ws + WS_BND);
    float* out_d = (float*)d_out;
    float* out_i = out_d + (size_t)BN * KOUT;

    hipLaunchKernelGGL(k_prep_all, dim3(64), dim3(1024), 0, stream,
                       x, tab, idx16, bnd);
    hipLaunchKernelGGL(knn_far_kernel, dim3(BN / 8), dim3(256), 0, stream,
                       tab, idx16, bnd, out_d, out_i);
}